// Round 1
// baseline (563.502 us; speedup 1.0000x reference)
//
#include <hip/hip_runtime.h>

#define B 64
#define K 8
#define V 128000
#define CH 4096
#define NCH 32   // ceil(V/CH) = 31.25 -> 32 (chunk 31 holds 1024 elems)

// ---------------------------------------------------------------------------
// Workspace layout:
//   [0 .. B*NCH) floats : chunkSums   (8 KB)
//   then B ints         : meta (num_accepted per batch)
//   then B ints         : counters (last-block-done), zeroed by k_init
// ---------------------------------------------------------------------------

// ---------------------------------------------------------------------------
// Kernel 1: parallel accept chain + counter init. One block, 512 threads:
// thread = (b,k); all 512 scattered gathers issue in ONE memory round trip
// (the old per-batch loop was an 8-deep dependent-load chain). na is derived
// from a wave ballot: 8 batches per wave, 8 bits per batch, na = first zero.
// ---------------------------------------------------------------------------
__global__ __launch_bounds__(512) void k_init(
    const int*   __restrict__ draft_tokens,
    const float* __restrict__ draft_probs,
    const float* __restrict__ oracle_probs,
    const float* __restrict__ uniforms,
    int* __restrict__ meta,
    int* __restrict__ counters,
    int* __restrict__ out_na)
{
  const int tid = threadIdx.x;          // 0..511
  if (tid < B) counters[tid] = 0;       // re-zero (ws is poisoned per iter)

  const int b = tid >> 3;               // 0..63
  const int k = tid & 7;                // 0..7
  int   t  = draft_tokens[b * K + k];
  float pd = draft_probs [((size_t)(b * K       + k)) * V + t];
  float po = oracle_probs[((size_t)(b * (K + 1) + k)) * V + t];
  bool accept = uniforms[b * K + k] < fminf(1.0f, po / pd);   // same math as before

  unsigned long long mask = __ballot(accept);   // 64 lanes = 8 batches
  const int g = (tid >> 3) & 7;                 // batch-within-wave
  unsigned m8 = (unsigned)((mask >> (g * 8)) & 0xFFull);
  int na = __ffs((~m8) & 0x1FF) - 1;            // leading-accept count, 0..8

  if (k == 0) { meta[b] = na; out_na[b] = na; }
}

// ---------------------------------------------------------------------------
// Kernel 2 (fused): per (batch, chunk) partial sums of final_dist, then the
// LAST finishing block per batch (device-scope atomic counter) runs the
// sampling phase inline (chunk-sum scan -> crossing chunk -> exact index ->
// token row). Sampling numerics are verbatim from the old k3 so token
// outputs remain bit-exact.
// ---------------------------------------------------------------------------
__global__ __launch_bounds__(256) void k_fused(
    const int*   __restrict__ draft_tokens,
    const float* __restrict__ draft_probs,
    const float* __restrict__ oracle_probs,
    const float* __restrict__ sample_u,
    const int*   __restrict__ meta,
    float* __restrict__ chunkSums,
    int*   __restrict__ counters,
    int*   __restrict__ out_tokens)
{
  const int b    = blockIdx.x >> 5;
  const int c    = blockIdx.x & 31;
  const int tid  = threadIdx.x;
  const int lane = tid & 63, w = tid >> 6;

  const int na   = meta[b];
  const bool acc = (na == K);
  const int row  = acc ? K : na;             // min(na, K-1) == na when na < K
  const float* orow = oracle_probs + ((size_t)(b * (K + 1) + row)) * V;
  const float* drow = draft_probs  + ((size_t)(b * K       + row)) * V;

  // ---- phase 1: chunk partial sum (identical numerics to old k2) ----------
  const int base = c * CH;
  float s = 0.f;
#pragma unroll
  for (int it = 0; it < 4; ++it) {
    int idx = base + it * 1024 + tid * 4;
    if (idx < V) {
      float4 o = *(const float4*)(orow + idx);
      if (acc) {
        s += (o.x + o.y) + (o.z + o.w);
      } else {
        float4 d = *(const float4*)(drow + idx);
        s += fmaxf(o.x - d.x, 0.f) + fmaxf(o.y - d.y, 0.f)
           + fmaxf(o.z - d.z, 0.f) + fmaxf(o.w - d.w, 0.f);
      }
    }
  }
  for (int off = 32; off > 0; off >>= 1) s += __shfl_down(s, off);
  __shared__ float wsum[4];
  if (lane == 0) wsum[w] = s;
  __syncthreads();

  __shared__ int sLastFlag;
  if (tid == 0) {
    chunkSums[b * NCH + c] = (wsum[0] + wsum[1]) + (wsum[2] + wsum[3]);
    __threadfence();                               // release: publish chunk sum
    int old = atomicAdd(&counters[b], 1);          // device-scope by default
    sLastFlag = (old == NCH - 1) ? 1 : 0;
  }
  __syncthreads();
  if (sLastFlag == 0) return;                      // uniform exit
  __threadfence();                                 // acquire: see all chunkSums

  // ---- phase 2: sampling (verbatim port of old k3) ------------------------
  __shared__ float sT, sBase;
  __shared__ int   sC, sIdx;
  __shared__ float sWS[4];

  if (w == 0) {
    float v = (lane < NCH) ? chunkSums[b * NCH + lane] : 0.f;
    float incl = v;
    for (int off = 1; off < NCH; off <<= 1) {
      float n = __shfl_up(incl, off);
      if (lane >= off) incl += n;
    }
    float S = __shfl(incl, NCH - 1);
    float T = acc ? sample_u[b] : sample_u[b] * S;   // unnormalized threshold
    unsigned long long m = __ballot(lane < NCH && incl >= T);
    if (lane == 0) {
      sT = T;
      if (m == 0ULL) { sC = -1; sIdx = V - 1; sBase = 0.f; }
    }
    if (m != 0ULL) {
      int cstar = __ffsll((long long)m) - 1;
      if (lane == cstar) {
        sC = cstar;
        sBase = incl - v;                       // exclusive prefix
        int fb = cstar * CH + CH - 1;           // fallback: end of chunk
        sIdx = fb < V ? fb : V - 1;
      }
    }
  }
  __syncthreads();

  const int cstar = sC;     // uniform across block
  int new_token;
  if (cstar >= 0) {
    const float T = sT;
    const int cbase = cstar * CH;
    const int estart = cbase + tid * 16;        // 16 contiguous elems / thread
    float vals[16];
    float s2 = 0.f;
#pragma unroll
    for (int j4 = 0; j4 < 4; ++j4) {
      int idx = estart + j4 * 4;
      float4 o = make_float4(0.f, 0.f, 0.f, 0.f);
      float4 d = make_float4(0.f, 0.f, 0.f, 0.f);
      if (idx < V) {
        o = *(const float4*)(orow + idx);
        if (!acc) d = *(const float4*)(drow + idx);
      }
      float v0 = acc ? o.x : fmaxf(o.x - d.x, 0.f);
      float v1 = acc ? o.y : fmaxf(o.y - d.y, 0.f);
      float v2 = acc ? o.z : fmaxf(o.z - d.z, 0.f);
      float v3 = acc ? o.w : fmaxf(o.w - d.w, 0.f);
      vals[j4 * 4 + 0] = v0; vals[j4 * 4 + 1] = v1;
      vals[j4 * 4 + 2] = v2; vals[j4 * 4 + 3] = v3;
      s2 += (v0 + v1) + (v2 + v3);
    }
    // block-wide exclusive prefix of per-thread sums
    float incl = s2;
    for (int off = 1; off < 64; off <<= 1) {
      float n = __shfl_up(incl, off);
      if (lane >= off) incl += n;
    }
    if (lane == 63) sWS[w] = incl;
    __syncthreads();
    float woff = 0.f;
    for (int i = 0; i < w; ++i) woff += sWS[i];
    float run = sBase + woff + (incl - s2);
    int found = -1;
#pragma unroll
    for (int j = 0; j < 16; ++j) {
      run += vals[j];
      if (found < 0 && run >= T) found = estart + j;
    }
    if (found >= 0 && found < V) atomicMin(&sIdx, found);
    __syncthreads();
    new_token = sIdx;
  } else {
    new_token = V - 1;
  }

  // token row: pos<na -> draft, pos==na -> new_token, else -1
  if (tid < K + 1) {
    int pos = tid, val;
    if (pos < na)       val = draft_tokens[b * K + pos];  // pos<na implies pos<K
    else if (pos == na) val = new_token;
    else                val = -1;
    out_tokens[b * (K + 1) + pos] = val;
  }
}

// ---------------------------------------------------------------------------
extern "C" void kernel_launch(void* const* d_in, const int* in_sizes, int n_in,
                              void* d_out, int out_size, void* d_ws, size_t ws_size,
                              hipStream_t stream) {
  const int*   draft_tokens = (const int*)  d_in[0];
  const float* draft_probs  = (const float*)d_in[1];
  /* d_in[2] = oracle_tokens (unused by the reference math) */
  const float* oracle_probs = (const float*)d_in[3];
  const float* uniforms     = (const float*)d_in[4];
  const float* sample_u     = (const float*)d_in[5];
  /* d_in[6] = num_draft_tokens == K (hardcoded) */

  int* out_tokens = (int*)d_out;                 // [B, K+1] = 576
  int* out_na     = out_tokens + B * (K + 1);    // [B]      = 64

  float* chunkSums = (float*)d_ws;               // B*NCH floats = 8 KB
  int*   meta      = (int*)d_ws + B * NCH;       // B ints
  int*   counters  = meta + B;                   // B ints

  k_init <<<1, 512, 0, stream>>>(draft_tokens, draft_probs, oracle_probs,
                                 uniforms, meta, counters, out_na);
  k_fused<<<B * NCH, 256, 0, stream>>>(draft_tokens, draft_probs, oracle_probs,
                                       sample_u, meta, chunkSums, counters,
                                       out_tokens);
}